// Round 5
// baseline (29005.194 us; speedup 1.0000x reference)
//
#include <hip/hip_runtime.h>
#include <cstdint>
#include <cstddef>

#define BB   128
#define IN   1024
#define HID  4096
#define OUTN 1024
#define TSTEPS 100
#define KC   384   // OpenBLAS SGEMM_DEFAULT_Q (Haswell/Zen kernels)

// ---------------- naive transpose: dst[c*R + r] = src[r*C + c] ----------------
__global__ __launch_bounds__(256) void ntrans_k(const float* __restrict__ src,
                                                float* __restrict__ dst,
                                                int R, int C) {
  int idx = blockIdx.x * 256 + threadIdx.x;   // grid sized exactly R*C/256
  int r = idx / C;
  int c = idx - r * C;
  dst[(size_t)c * R + r] = src[idx];
}

// f32 LIF exactly mirroring the reference op order (no FMA contraction).
__device__ __forceinline__ unsigned char lif_f32(float I, float& v, float& r) {
  bool active = I > 0.0f;
  bool refrac = r > 0.0f;
  float vi = __fadd_rn(__fmul_rn(v, 0.95f), I);
  bool fired = active && !refrac && (vi >= 1.0f);
  float vn = !active ? v : ((refrac || fired) ? 0.0f : vi);
  float rn = !active ? r : (refrac ? (r - 1.0f) : (fired ? 2.0f : r));
  v = vn; r = rn;
  return fired ? (unsigned char)1 : (unsigned char)0;
}

// ---------------- encode: one thread per (b,i), in-place refractory ----------------
__global__ __launch_bounds__(256) void encode_k(const float* __restrict__ noise_t,
                                                const float* __restrict__ x,
                                                float* __restrict__ rin,
                                                unsigned char* __restrict__ in_spk) {
  int gi = blockIdx.x * 256 + threadIdx.x;    // gi = b*IN + i, grid = BB*IN/256
  float p = __fmul_rn(x[gi], 100.0f);
  p = fminf(fmaxf(p, 0.0f), 100.0f);
  p = __fmul_rn(p, 0.001f);
  bool s = noise_t[gi] < p;                   // Bernoulli encode (strict <)
  float r = rin[gi];
  bool refrac = r > 0.0f;
  bool fired = s && !refrac;                  // input-layer v == 0 always (proven)
  rin[gi] = !s ? r : (refrac ? (r - 1.0f) : 2.0f);
  in_spk[gi] = fired ? 1 : 0;
}

// ---------------- hidden layer: kc-panel blocked sequential-k sum + LIF ----------
// Per element, emulate BLAS sgemm: within each kc-panel a single f32 accumulator,
// ascending k, gated adds (fma(1,w,acc)==add, fma(0,w,acc)==acc, both exact);
// panels combined via one rounded add each: ((P0+P1)+P2).
__global__ __launch_bounds__(256) void hidden_k(const unsigned char* __restrict__ in_spk,
                                                const float* __restrict__ W1T,
                                                float* __restrict__ v_h,
                                                float* __restrict__ r_h,
                                                unsigned char* __restrict__ hid_spk) {
  int h = blockIdx.x * 256 + threadIdx.x;
  int b = blockIdx.y;
  __shared__ unsigned char s_sh[IN];
  for (int k = threadIdx.x; k < IN; k += 256) s_sh[k] = in_spk[(size_t)b * IN + k];
  __syncthreads();
  float total = 0.0f;
  for (int p0 = 0; p0 < IN; p0 += KC) {
    int pend = (p0 + KC < IN) ? (p0 + KC) : IN;
    float part = 0.0f;
    for (int k = p0; k < pend; k++) {
      if (s_sh[k]) part = __fadd_rn(part, W1T[(size_t)k * HID + h]);
    }
    total = __fadd_rn(total, part);   // first panel: rn(0+P0)=P0 exact
  }
  size_t idx = (size_t)b * HID + h;
  float v = v_h[idx], r = r_h[idx];
  hid_spk[idx] = lif_f32(total, v, r);
  v_h[idx] = v; r_h[idx] = r;
}

// ---------------- output layer: kc-panel blocked sum + LIF + count ----------------
__global__ __launch_bounds__(256) void out_k(const unsigned char* __restrict__ hid_spk,
                                             const float* __restrict__ W2T,
                                             float* __restrict__ v_o,
                                             float* __restrict__ r_o,
                                             float* __restrict__ out_acc) {
  int o = blockIdx.x * 256 + threadIdx.x;
  int b = blockIdx.y;
  __shared__ unsigned char s_sh[HID];
  for (int k = threadIdx.x; k < HID; k += 256) s_sh[k] = hid_spk[(size_t)b * HID + k];
  __syncthreads();
  float total = 0.0f;
  for (int p0 = 0; p0 < HID; p0 += KC) {
    int pend = (p0 + KC < HID) ? (p0 + KC) : HID;
    float part = 0.0f;
    for (int k = p0; k < pend; k++) {
      if (s_sh[k]) part = __fadd_rn(part, W2T[(size_t)k * OUTN + o]);
    }
    total = __fadd_rn(total, part);
  }
  size_t idx = (size_t)b * OUTN + o;
  float v = v_o[idx], r = r_o[idx];
  unsigned char fired = lif_f32(total, v, r);
  v_o[idx] = v; r_o[idx] = r;
  if (fired) out_acc[idx] = __fadd_rn(out_acc[idx], 1.0f);  // exact int count
}

// ---------------- STDP kernels (t % 10 == 0), f32 ----------------
__global__ void zero2_k(int* flags) { flags[0] = 0; flags[1] = 0; }

__global__ __launch_bounds__(256) void stats_k(
    const unsigned char* __restrict__ in_spk, const unsigned char* __restrict__ hid_spk,
    float* __restrict__ pre_m, float* __restrict__ post_m,
    float* __restrict__ tp, float* __restrict__ tn, int* __restrict__ flags) {
  int c = blockIdx.x * 256 + threadIdx.x;
  if (c < IN) {
    int i = c, cnt = 0;
    for (int b = 0; b < BB; b++) cnt += in_spk[(size_t)b * IN + i];
    float pm = __fdiv_rn((float)cnt, 128.0f);       // exact (pow2)
    pre_m[i] = pm;
    tp[i] = __fadd_rn(__fmul_rn(0.9f, tp[i]), pm);  // tp_n committed (stdp step)
    if (cnt > 0) atomicOr(flags + 0, 1);
  } else if (c < IN + HID) {
    int h = c - IN, cnt = 0;
    for (int b = 0; b < BB; b++) cnt += hid_spk[(size_t)b * HID + h];
    float pm = __fdiv_rn((float)cnt, 128.0f);
    post_m[h] = pm;
    tn[h] = __fadd_rn(__fmul_rn(0.9f, tn[h]), pm);
    if (cnt > 0) atomicOr(flags + 1, 1);
  }
}

__global__ __launch_bounds__(256) void apply_k(
    float* __restrict__ W1T,
    const float* __restrict__ tp, const float* __restrict__ tn,
    const float* __restrict__ pre_m, const float* __restrict__ post_m,
    const int* __restrict__ flags) {
  if (!(flags[0] && flags[1])) return;   // 'both' gate
  size_t idx = (size_t)blockIdx.x * 256 + threadIdx.x;  // i*HID + h layout
  int i = (int)(idx >> 12);
  int h = (int)(idx & 4095);
  float a  = __fmul_rn(tp[i], post_m[h]);     // tp already == tp_n
  float b2 = __fmul_rn(pre_m[i], tn[h]);      // tn already == tn_n
  float d  = __fmul_rn(0.001f, __fsub_rn(a, b2));
  float w  = __fadd_rn(W1T[idx], d);
  w = fminf(fmaxf(w, -1.0f), 1.0f);           // jnp.clip: max then min
  W1T[idx] = w;
}

__global__ __launch_bounds__(256) void scale_k(const float* __restrict__ acc,
                                               float* __restrict__ out) {
  int j = blockIdx.x * 256 + threadIdx.x;
  out[j] = __fdiv_rn(acc[j], 100.0f);
}

// ---------------- host launcher ----------------
extern "C" void kernel_launch(void* const* d_in, const int* in_sizes, int n_in,
                              void* d_out, int out_size, void* d_ws, size_t ws_size,
                              hipStream_t stream) {
  (void)in_sizes; (void)n_in; (void)out_size; (void)ws_size;
  const float* x     = (const float*)d_in[0];
  const float* W1    = (const float*)d_in[1];
  const float* W2    = (const float*)d_in[2];
  const float* noise = (const float*)d_in[3];

  char* ws = (char*)d_ws;
  size_t off = 0;
  auto alloc = [&](size_t bytes) -> char* {
    char* p = ws + off;
    off += (bytes + 255) & ~(size_t)255;
    return p;
  };
  float* W1T   = (float*)alloc((size_t)IN * HID * 4);     // 16 MB working copy (i-major)
  float* W2T   = (float*)alloc((size_t)HID * OUTN * 4);   // 16 MB (h-major)
  float* v_h   = (float*)alloc((size_t)BB * HID * 4);
  float* r_h   = (float*)alloc((size_t)BB * HID * 4);
  float* v_o   = (float*)alloc((size_t)BB * OUTN * 4);
  float* r_o   = (float*)alloc((size_t)BB * OUTN * 4);
  float* rin   = (float*)alloc((size_t)BB * IN * 4);      // in-place (one owner thread)
  float* acc   = (float*)alloc((size_t)BB * OUTN * 4);
  float* tp    = (float*)alloc((size_t)IN * 4);
  float* tn    = (float*)alloc((size_t)HID * 4);
  float* pre_m = (float*)alloc((size_t)IN * 4);
  float* post_m= (float*)alloc((size_t)HID * 4);
  unsigned char* in_spk  = (unsigned char*)alloc((size_t)BB * IN);
  unsigned char* hid_spk = (unsigned char*)alloc((size_t)BB * HID);
  int* flags   = (int*)alloc(2 * sizeof(int));

  // zero all state (ws is poisoned before every call)
  hipMemsetAsync(v_h, 0, (size_t)BB * HID * 4, stream);
  hipMemsetAsync(r_h, 0, (size_t)BB * HID * 4, stream);
  hipMemsetAsync(v_o, 0, (size_t)BB * OUTN * 4, stream);
  hipMemsetAsync(r_o, 0, (size_t)BB * OUTN * 4, stream);
  hipMemsetAsync(rin, 0, (size_t)BB * IN * 4, stream);
  hipMemsetAsync(acc, 0, (size_t)BB * OUTN * 4, stream);
  hipMemsetAsync(tp,  0, (size_t)IN * 4, stream);
  hipMemsetAsync(tn,  0, (size_t)HID * 4, stream);

  // W1 (HID x IN) -> W1T (IN x HID): R=HID, C=IN. W2 (OUTN x HID) -> W2T (HID x OUTN).
  ntrans_k<<<(HID * IN) / 256, 256, 0, stream>>>(W1, W1T, HID, IN);
  ntrans_k<<<(OUTN * HID) / 256, 256, 0, stream>>>(W2, W2T, OUTN, HID);

  for (int t = 0; t < TSTEPS; t++) {
    const float* nz = noise + (size_t)t * BB * IN;
    encode_k<<<(BB * IN) / 256, 256, 0, stream>>>(nz, x, rin, in_spk);
    hidden_k<<<dim3(HID / 256, BB), 256, 0, stream>>>(in_spk, W1T, v_h, r_h, hid_spk);
    out_k<<<dim3(OUTN / 256, BB), 256, 0, stream>>>(hid_spk, W2T, v_o, r_o, acc);
    if (t % 10 == 0) {
      zero2_k<<<1, 1, 0, stream>>>(flags);
      stats_k<<<(IN + HID + 255) / 256, 256, 0, stream>>>(in_spk, hid_spk,
                                                          pre_m, post_m, tp, tn, flags);
      apply_k<<<(IN * HID) / 256, 256, 0, stream>>>(W1T, tp, tn, pre_m, post_m, flags);
    }
  }
  scale_k<<<(BB * OUTN) / 256, 256, 0, stream>>>(acc, (float*)d_out);
}